// Round 1
// baseline (6608.649 us; speedup 1.0000x reference)
//
#include <hip/hip_runtime.h>
#include <hip/hip_bf16.h>
#include <cstdint>

#define N_NODES 50000
#define N_EDGES 800000
#define ET_EDGES (N_EDGES + N_NODES)   // with self-loops
#define FDIM 256
#define BN_EPS 1e-5f

__device__ __forceinline__ float lrelu(float x) { return x >= 0.f ? x : 0.2f * x; }

// float atomic max via ordered-int mapping (valid incl. -inf/NaN-bits init 0xFFFFFFFF)
__device__ __forceinline__ void atomicMaxF(float* addr, float val) {
    if (val >= 0.f) atomicMax((int*)addr, __float_as_int(val));
    else            atomicMin((unsigned int*)addr, (unsigned int)__float_as_int(val));
}

// ---------------- BN param prep: scale/shift per feature, both layers ----------------
__global__ void prep_bn_kernel(const float* __restrict__ b1, const float* __restrict__ g1,
                               const float* __restrict__ be1, const float* __restrict__ m1,
                               const float* __restrict__ v1,
                               const float* __restrict__ b2, const float* __restrict__ g2,
                               const float* __restrict__ be2, const float* __restrict__ m2,
                               const float* __restrict__ v2,
                               float* sc1, float* sh1, float* sc2, float* sh2) {
    int f = threadIdx.x;
    float s1 = rsqrtf(v1[f] + BN_EPS) * g1[f];
    sc1[f] = s1;
    sh1[f] = (b1[f] - m1[f]) * s1 + be1[f];
    float s2 = rsqrtf(v2[f] + BN_EPS) * g2[f];
    sc2[f] = s2;
    sh2[f] = (b2[f] - m2[f]) * s2 + be2[f];
}

// ---------------- fp32 tiled GEMM: Hout[n x 256] = A[n x K] @ W[K x 256] ----------------
template <int K>
__global__ __launch_bounds__(256) void gemm_kernel(const float* __restrict__ A,
                                                   const float* __restrict__ W,
                                                   float* __restrict__ Hout, int n) {
    constexpr int BK = 32;
    __shared__ __align__(16) float As[BK][68];  // [k][m], padded stride 68 (16B-aligned rows)
    __shared__ __align__(16) float Ws[BK][68];  // [k][n]
    const int tid = threadIdx.x;
    const int bm = blockIdx.x * 64;
    const int bn = blockIdx.y * 64;
    const int ty = tid >> 4;   // 0..15 row group
    const int tx = tid & 15;   // 0..15 col group
    float acc[4][4] = {{0.f}};

    for (int k0 = 0; k0 < K; k0 += BK) {
#pragma unroll
        for (int l = 0; l < 2; ++l) {
            int f = tid + l * 256;
            // A tile: 64 rows x 32 k  (8 float4 per row)
            int row = f >> 3, kc = (f & 7) * 4;
            int gr = bm + row;
            float4 av = make_float4(0.f, 0.f, 0.f, 0.f);
            if (gr < n) av = *(const float4*)(A + (size_t)gr * K + k0 + kc);
            As[kc + 0][row] = av.x;
            As[kc + 1][row] = av.y;
            As[kc + 2][row] = av.z;
            As[kc + 3][row] = av.w;
            // W tile: 32 k x 64 cols (16 float4 per k-row)
            int kr = f >> 4, c = (f & 15) * 4;
            *(float4*)&Ws[kr][c] = *(const float4*)(W + (size_t)(k0 + kr) * 256 + bn + c);
        }
        __syncthreads();
#pragma unroll
        for (int kk = 0; kk < BK; ++kk) {
            float4 a4 = *(const float4*)&As[kk][ty * 4];
            float4 w4 = *(const float4*)&Ws[kk][tx * 4];
            float am[4] = {a4.x, a4.y, a4.z, a4.w};
            float wn[4] = {w4.x, w4.y, w4.z, w4.w};
#pragma unroll
            for (int i = 0; i < 4; ++i)
#pragma unroll
                for (int j = 0; j < 4; ++j) acc[i][j] = fmaf(am[i], wn[j], acc[i][j]);
        }
        __syncthreads();
    }
#pragma unroll
    for (int i = 0; i < 4; ++i) {
        int gr = bm + ty * 4 + i;
        if (gr < n) {
            float4 v = make_float4(acc[i][0], acc[i][1], acc[i][2], acc[i][3]);
            *(float4*)(Hout + (size_t)gr * 256 + bn + tx * 4) = v;
        }
    }
}

// ---------------- per-node attention dots: asrc/adst [N][4] ----------------
__global__ __launch_bounds__(256) void adot_kernel(const float* __restrict__ h,
                                                   const float* __restrict__ a_src,
                                                   const float* __restrict__ a_dst,
                                                   float* __restrict__ asrc,
                                                   float* __restrict__ adst, int n) {
    int node = blockIdx.x * 4 + (threadIdx.x >> 6);
    if (node >= n) return;
    int lane = threadIdx.x & 63;
    float ps[4], pd[4];
#pragma unroll
    for (int hd = 0; hd < 4; ++hd) {
        float hv = h[(size_t)node * 256 + hd * 64 + lane];
        ps[hd] = hv * a_src[hd * 64 + lane];
        pd[hd] = hv * a_dst[hd * 64 + lane];
    }
#pragma unroll
    for (int off = 32; off > 0; off >>= 1) {
#pragma unroll
        for (int hd = 0; hd < 4; ++hd) {
            ps[hd] += __shfl_down(ps[hd], off);
            pd[hd] += __shfl_down(pd[hd], off);
        }
    }
    if (lane == 0) {
        *(float4*)(asrc + node * 4) = make_float4(ps[0], ps[1], ps[2], ps[3]);
        *(float4*)(adst + node * 4) = make_float4(pd[0], pd[1], pd[2], pd[3]);
    }
}

// ---------------- edge pass 1: segment max of leaky_relu(asrc[s]+adst[d]) ----------------
__global__ __launch_bounds__(256) void edge_max_kernel(const int* __restrict__ ei,
                                                       const float* __restrict__ asrc,
                                                       const float* __restrict__ adst,
                                                       float* __restrict__ emax) {
    int e = blockIdx.x * 256 + threadIdx.x;
    if (e >= ET_EDGES) return;
    int s, d;
    if (e < N_EDGES) { s = ei[e]; d = ei[N_EDGES + e]; }
    else             { s = d = e - N_EDGES; }
    float4 as = *(const float4*)(asrc + (size_t)s * 4);
    float4 ad = *(const float4*)(adst + (size_t)d * 4);
    atomicMaxF(&emax[d * 4 + 0], lrelu(as.x + ad.x));
    atomicMaxF(&emax[d * 4 + 1], lrelu(as.y + ad.y));
    atomicMaxF(&emax[d * 4 + 2], lrelu(as.z + ad.z));
    atomicMaxF(&emax[d * 4 + 3], lrelu(as.w + ad.w));
}

// ---------------- edge pass 2: denom = segment sum of exp(e - emax) ----------------
__global__ __launch_bounds__(256) void edge_sum_kernel(const int* __restrict__ ei,
                                                       const float* __restrict__ asrc,
                                                       const float* __restrict__ adst,
                                                       const float* __restrict__ emax,
                                                       float* __restrict__ denom) {
    int e = blockIdx.x * 256 + threadIdx.x;
    if (e >= ET_EDGES) return;
    int s, d;
    if (e < N_EDGES) { s = ei[e]; d = ei[N_EDGES + e]; }
    else             { s = d = e - N_EDGES; }
    float4 as = *(const float4*)(asrc + (size_t)s * 4);
    float4 ad = *(const float4*)(adst + (size_t)d * 4);
    float4 mx = *(const float4*)(emax + (size_t)d * 4);
    unsafeAtomicAdd(&denom[d * 4 + 0], __expf(lrelu(as.x + ad.x) - mx.x));
    unsafeAtomicAdd(&denom[d * 4 + 1], __expf(lrelu(as.y + ad.y) - mx.y));
    unsafeAtomicAdd(&denom[d * 4 + 2], __expf(lrelu(as.z + ad.z) - mx.z));
    unsafeAtomicAdd(&denom[d * 4 + 3], __expf(lrelu(as.w + ad.w) - mx.w));
}

// ---------------- edge pass 3: agg[d] += h[s] * alpha  (one wave per edge) ----------------
__global__ __launch_bounds__(256) void edge_agg_kernel(const int* __restrict__ ei,
                                                       const float* __restrict__ asrc,
                                                       const float* __restrict__ adst,
                                                       const float* __restrict__ emax,
                                                       const float* __restrict__ denom,
                                                       const float* __restrict__ h,
                                                       float* __restrict__ agg) {
    int e = blockIdx.x * 4 + (threadIdx.x >> 6);
    if (e >= ET_EDGES) return;
    int lane = threadIdx.x & 63;
    int s, d;
    if (e < N_EDGES) { s = ei[e]; d = ei[N_EDGES + e]; }
    else             { s = d = e - N_EDGES; }
    float4 as = *(const float4*)(asrc + (size_t)s * 4);
    float4 ad = *(const float4*)(adst + (size_t)d * 4);
    float4 mx = *(const float4*)(emax + (size_t)d * 4);
    float4 dn = *(const float4*)(denom + (size_t)d * 4);
    float al[4];
    al[0] = __expf(lrelu(as.x + ad.x) - mx.x) / (dn.x + 1e-16f);
    al[1] = __expf(lrelu(as.y + ad.y) - mx.y) / (dn.y + 1e-16f);
    al[2] = __expf(lrelu(as.z + ad.z) - mx.z) / (dn.z + 1e-16f);
    al[3] = __expf(lrelu(as.w + ad.w) - mx.w) / (dn.w + 1e-16f);
    float a = al[lane >> 4];  // lane covers cols [4*lane, 4*lane+4) -> head = lane/16
    float4 hv = *(const float4*)(h + (size_t)s * 256 + lane * 4);
    float* p = agg + (size_t)d * 256 + lane * 4;
    unsafeAtomicAdd(p + 0, hv.x * a);
    unsafeAtomicAdd(p + 1, hv.y * a);
    unsafeAtomicAdd(p + 2, hv.z * a);
    unsafeAtomicAdd(p + 3, hv.w * a);
}

// ---------------- BN (eval) + ReLU, in place, layer-1 ----------------
__global__ __launch_bounds__(256) void bn_relu_kernel(float* __restrict__ io,
                                                      const float* __restrict__ scale,
                                                      const float* __restrict__ shift) {
    int i = blockIdx.x * 256 + threadIdx.x;  // float4 index
    if (i >= N_NODES * 64) return;
    float4 v = ((const float4*)io)[i];
    int f4 = i & 63;
    float4 sc = ((const float4*)scale)[f4];
    float4 sh = ((const float4*)shift)[f4];
    v.x = fmaxf(fmaf(v.x, sc.x, sh.x), 0.f);
    v.y = fmaxf(fmaf(v.y, sc.y, sh.y), 0.f);
    v.z = fmaxf(fmaf(v.z, sc.z, sh.z), 0.f);
    v.w = fmaxf(fmaf(v.w, sc.w, sh.w), 0.f);
    ((float4*)io)[i] = v;
}

// ---------------- BN + ReLU + log_softmax, in place, layer-2 (block per node) ----------------
__global__ __launch_bounds__(256) void final_kernel(float* __restrict__ io,
                                                    const float* __restrict__ scale,
                                                    const float* __restrict__ shift) {
    int node = blockIdx.x;
    int f = threadIdx.x;
    float* row = io + (size_t)node * 256;
    float t = fmaxf(fmaf(row[f], scale[f], shift[f]), 0.f);
    __shared__ float redm[4];
    __shared__ float reds[4];
    int w = threadIdx.x >> 6, lane = threadIdx.x & 63;
    float m = t;
#pragma unroll
    for (int off = 32; off > 0; off >>= 1) m = fmaxf(m, __shfl_down(m, off));
    if (lane == 0) redm[w] = m;
    __syncthreads();
    m = fmaxf(fmaxf(redm[0], redm[1]), fmaxf(redm[2], redm[3]));
    float ex = __expf(t - m);
    float ssum = ex;
#pragma unroll
    for (int off = 32; off > 0; off >>= 1) ssum += __shfl_down(ssum, off);
    if (lane == 0) reds[w] = ssum;
    __syncthreads();
    ssum = reds[0] + reds[1] + reds[2] + reds[3];
    row[f] = t - m - logf(ssum);
}

extern "C" void kernel_launch(void* const* d_in, const int* in_sizes, int n_in,
                              void* d_out, int out_size, void* d_ws, size_t ws_size,
                              hipStream_t stream) {
    (void)in_sizes; (void)n_in; (void)out_size; (void)ws_size;
    const float* x   = (const float*)d_in[0];
    const int*   ei  = (const int*)d_in[1];
    const float* W1  = (const float*)d_in[2];
    const float* as1 = (const float*)d_in[3];
    const float* ad1 = (const float*)d_in[4];
    const float* b1  = (const float*)d_in[5];
    const float* g1  = (const float*)d_in[6];
    const float* be1 = (const float*)d_in[7];
    const float* m1  = (const float*)d_in[8];
    const float* v1  = (const float*)d_in[9];
    const float* W2  = (const float*)d_in[10];
    const float* as2 = (const float*)d_in[11];
    const float* ad2 = (const float*)d_in[12];
    const float* b2  = (const float*)d_in[13];
    const float* g2  = (const float*)d_in[14];
    const float* be2 = (const float*)d_in[15];
    const float* m2  = (const float*)d_in[16];
    const float* v2  = (const float*)d_in[17];

    float* out = (float*)d_out;
    // workspace layout (floats): h [N*256] | asrc [N*4] | adst [N*4] | emax [N*4] | denom [N*4] | sc1,sh1,sc2,sh2 [256 ea]
    float* h     = (float*)d_ws;
    float* asrc  = h + (size_t)N_NODES * FDIM;
    float* adst  = asrc + N_NODES * 4;
    float* emax  = adst + N_NODES * 4;
    float* denom = emax + N_NODES * 4;
    float* sc1   = denom + N_NODES * 4;
    float* sh1   = sc1 + 256;
    float* sc2   = sh1 + 256;
    float* sh2   = sc2 + 256;

    prep_bn_kernel<<<1, 256, 0, stream>>>(b1, g1, be1, m1, v1, b2, g2, be2, m2, v2,
                                          sc1, sh1, sc2, sh2);

    dim3 ggrid((N_NODES + 63) / 64, 4);
    const int eb = (ET_EDGES + 255) / 256;
    const int ab = (ET_EDGES + 3) / 4;

    // ---------------- layer 1 ----------------
    gemm_kernel<128><<<ggrid, 256, 0, stream>>>(x, W1, h, N_NODES);
    adot_kernel<<<(N_NODES + 3) / 4, 256, 0, stream>>>(h, as1, ad1, asrc, adst, N_NODES);
    hipMemsetAsync(emax, 0xFF, N_NODES * 4 * sizeof(float), stream);   // -inf-equivalent
    hipMemsetAsync(denom, 0, N_NODES * 4 * sizeof(float), stream);
    hipMemsetAsync(out, 0, (size_t)N_NODES * FDIM * sizeof(float), stream);
    edge_max_kernel<<<eb, 256, 0, stream>>>(ei, asrc, adst, emax);
    edge_sum_kernel<<<eb, 256, 0, stream>>>(ei, asrc, adst, emax, denom);
    edge_agg_kernel<<<ab, 256, 0, stream>>>(ei, asrc, adst, emax, denom, h, out);
    bn_relu_kernel<<<(N_NODES * 64) / 256, 256, 0, stream>>>(out, sc1, sh1);

    // ---------------- layer 2 ----------------
    gemm_kernel<256><<<ggrid, 256, 0, stream>>>(out, W2, h, N_NODES);
    adot_kernel<<<(N_NODES + 3) / 4, 256, 0, stream>>>(h, as2, ad2, asrc, adst, N_NODES);
    hipMemsetAsync(emax, 0xFF, N_NODES * 4 * sizeof(float), stream);
    hipMemsetAsync(denom, 0, N_NODES * 4 * sizeof(float), stream);
    edge_max_kernel<<<eb, 256, 0, stream>>>(ei, asrc, adst, emax);
    edge_sum_kernel<<<eb, 256, 0, stream>>>(ei, asrc, adst, emax, denom);
    hipMemsetAsync(out, 0, (size_t)N_NODES * FDIM * sizeof(float), stream);  // after gemm2 read
    edge_agg_kernel<<<ab, 256, 0, stream>>>(ei, asrc, adst, emax, denom, h, out);
    final_kernel<<<N_NODES, 256, 0, stream>>>(out, sc2, sh2);
}

// Round 2
// 814.125 us; speedup vs baseline: 8.1175x; 8.1175x over previous
//
#include <hip/hip_runtime.h>
#include <hip/hip_bf16.h>
#include <cstdint>

#define N_NODES 50000
#define N_EDGES 800000
#define ET_EDGES (N_EDGES + N_NODES)   // with self-loops
#define FDIM 256
#define BN_EPS 1e-5f

__device__ __forceinline__ float lrelu(float x) { return x >= 0.f ? x : 0.2f * x; }

// ---------------- BN param prep: scale/shift per feature, both layers ----------------
__global__ void prep_bn_kernel(const float* __restrict__ b1, const float* __restrict__ g1,
                               const float* __restrict__ be1, const float* __restrict__ m1,
                               const float* __restrict__ v1,
                               const float* __restrict__ b2, const float* __restrict__ g2,
                               const float* __restrict__ be2, const float* __restrict__ m2,
                               const float* __restrict__ v2,
                               float* sc1, float* sh1, float* sc2, float* sh2) {
    int f = threadIdx.x;
    float s1 = rsqrtf(v1[f] + BN_EPS) * g1[f];
    sc1[f] = s1;
    sh1[f] = (b1[f] - m1[f]) * s1 + be1[f];
    float s2 = rsqrtf(v2[f] + BN_EPS) * g2[f];
    sc2[f] = s2;
    sh2[f] = (b2[f] - m2[f]) * s2 + be2[f];
}

// ---------------- CSR build ----------------
__global__ __launch_bounds__(256) void deg_kernel(const int* __restrict__ ei,
                                                  int* __restrict__ deg) {
    int e = blockIdx.x * 256 + threadIdx.x;
    if (e >= ET_EDGES) return;
    int d = (e < N_EDGES) ? ei[N_EDGES + e] : (e - N_EDGES);
    atomicAdd(&deg[d], 1);
}

// single-block exclusive scan of deg[N_NODES] -> offs[N_NODES+1]
__global__ __launch_bounds__(1024) void scan_kernel(const int* __restrict__ deg,
                                                    int* __restrict__ offs) {
    __shared__ int sums[1024];
    const int t = threadIdx.x;
    constexpr int CH = (N_NODES + 1023) / 1024;  // 49
    int local[CH];
    int base = t * CH;
    int s = 0;
#pragma unroll
    for (int i = 0; i < CH; ++i) {
        int idx = base + i;
        int v = (idx < N_NODES) ? deg[idx] : 0;
        local[i] = v;
        s += v;
    }
    sums[t] = s;
    __syncthreads();
    for (int off = 1; off < 1024; off <<= 1) {
        int y = (t >= off) ? sums[t - off] : 0;
        __syncthreads();
        sums[t] += y;
        __syncthreads();
    }
    int carry = sums[t] - s;  // exclusive prefix
#pragma unroll
    for (int i = 0; i < CH; ++i) {
        int idx = base + i;
        if (idx < N_NODES) offs[idx] = carry;
        carry += local[i];
    }
    if (t == 0) offs[N_NODES] = ET_EDGES;
}

__global__ __launch_bounds__(256) void scatter_kernel(const int* __restrict__ ei,
                                                      const int* __restrict__ offs,
                                                      int* __restrict__ cursor,
                                                      int* __restrict__ csr) {
    int e = blockIdx.x * 256 + threadIdx.x;
    if (e >= ET_EDGES) return;
    int s, d;
    if (e < N_EDGES) { s = ei[e]; d = ei[N_EDGES + e]; }
    else             { s = d = e - N_EDGES; }
    int pos = offs[d] + atomicAdd(&cursor[d], 1);
    csr[pos] = s;
}

// ---------------- fp32 tiled GEMM: Hout[n x 256] = A[n x K] @ W[K x 256] ----------------
template <int K>
__global__ __launch_bounds__(256) void gemm_kernel(const float* __restrict__ A,
                                                   const float* __restrict__ W,
                                                   float* __restrict__ Hout, int n) {
    constexpr int BK = 32;
    __shared__ __align__(16) float As[BK][68];
    __shared__ __align__(16) float Ws[BK][68];
    const int tid = threadIdx.x;
    const int bm = blockIdx.x * 64;
    const int bn = blockIdx.y * 64;
    const int ty = tid >> 4;
    const int tx = tid & 15;
    float acc[4][4] = {{0.f}};

    for (int k0 = 0; k0 < K; k0 += BK) {
#pragma unroll
        for (int l = 0; l < 2; ++l) {
            int f = tid + l * 256;
            int row = f >> 3, kc = (f & 7) * 4;
            int gr = bm + row;
            float4 av = make_float4(0.f, 0.f, 0.f, 0.f);
            if (gr < n) av = *(const float4*)(A + (size_t)gr * K + k0 + kc);
            As[kc + 0][row] = av.x;
            As[kc + 1][row] = av.y;
            As[kc + 2][row] = av.z;
            As[kc + 3][row] = av.w;
            int kr = f >> 4, c = (f & 15) * 4;
            *(float4*)&Ws[kr][c] = *(const float4*)(W + (size_t)(k0 + kr) * 256 + bn + c);
        }
        __syncthreads();
#pragma unroll
        for (int kk = 0; kk < BK; ++kk) {
            float4 a4 = *(const float4*)&As[kk][ty * 4];
            float4 w4 = *(const float4*)&Ws[kk][tx * 4];
            float am[4] = {a4.x, a4.y, a4.z, a4.w};
            float wn[4] = {w4.x, w4.y, w4.z, w4.w};
#pragma unroll
            for (int i = 0; i < 4; ++i)
#pragma unroll
                for (int j = 0; j < 4; ++j) acc[i][j] = fmaf(am[i], wn[j], acc[i][j]);
        }
        __syncthreads();
    }
#pragma unroll
    for (int i = 0; i < 4; ++i) {
        int gr = bm + ty * 4 + i;
        if (gr < n) {
            float4 v = make_float4(acc[i][0], acc[i][1], acc[i][2], acc[i][3]);
            *(float4*)(Hout + (size_t)gr * 256 + bn + tx * 4) = v;
        }
    }
}

// ---------------- per-node attention dots: asrc/adst [N][4] ----------------
__global__ __launch_bounds__(256) void adot_kernel(const float* __restrict__ h,
                                                   const float* __restrict__ a_src,
                                                   const float* __restrict__ a_dst,
                                                   float* __restrict__ asrc,
                                                   float* __restrict__ adst, int n) {
    int node = blockIdx.x * 4 + (threadIdx.x >> 6);
    if (node >= n) return;
    int lane = threadIdx.x & 63;
    float ps[4], pd[4];
#pragma unroll
    for (int hd = 0; hd < 4; ++hd) {
        float hv = h[(size_t)node * 256 + hd * 64 + lane];
        ps[hd] = hv * a_src[hd * 64 + lane];
        pd[hd] = hv * a_dst[hd * 64 + lane];
    }
#pragma unroll
    for (int off = 32; off > 0; off >>= 1) {
#pragma unroll
        for (int hd = 0; hd < 4; ++hd) {
            ps[hd] += __shfl_down(ps[hd], off);
            pd[hd] += __shfl_down(pd[hd], off);
        }
    }
    if (lane == 0) {
        *(float4*)(asrc + node * 4) = make_float4(ps[0], ps[1], ps[2], ps[3]);
        *(float4*)(adst + node * 4) = make_float4(pd[0], pd[1], pd[2], pd[3]);
    }
}

// ---------------- fused gather: softmax over incoming edges + aggregate + epilogue ----
// One wave per destination node. FINAL=false: BN+ReLU.  FINAL=true: BN+ReLU+log_softmax.
template <bool FINAL>
__global__ __launch_bounds__(256) void gat_gather_kernel(const int* __restrict__ offs,
                                                         const int* __restrict__ csr,
                                                         const float* __restrict__ asrc,
                                                         const float* __restrict__ adst,
                                                         const float* __restrict__ h,
                                                         const float* __restrict__ scale,
                                                         const float* __restrict__ shift,
                                                         float* __restrict__ outp) {
    int node = blockIdx.x * 4 + (threadIdx.x >> 6);
    if (node >= N_NODES) return;
    int lane = threadIdx.x & 63;
    int beg = offs[node], end = offs[node + 1];
    float4 ad = *(const float4*)(adst + (size_t)node * 4);

    // ---- phase 1: per-head max over incoming edges (lane-parallel) ----
    float m0 = -3.4e38f, m1 = -3.4e38f, m2 = -3.4e38f, m3 = -3.4e38f;
    float c0 = 0.f, c1 = 0.f, c2 = 0.f, c3 = 0.f;  // cached scores, first iter
    bool has = (beg + lane) < end;
    if (has) {
        int s = csr[beg + lane];
        float4 as = *(const float4*)(asrc + (size_t)s * 4);
        c0 = lrelu(as.x + ad.x); c1 = lrelu(as.y + ad.y);
        c2 = lrelu(as.z + ad.z); c3 = lrelu(as.w + ad.w);
        m0 = c0; m1 = c1; m2 = c2; m3 = c3;
    }
    for (int e = beg + lane + 64; e < end; e += 64) {  // rare: deg > 64
        int s = csr[e];
        float4 as = *(const float4*)(asrc + (size_t)s * 4);
        m0 = fmaxf(m0, lrelu(as.x + ad.x)); m1 = fmaxf(m1, lrelu(as.y + ad.y));
        m2 = fmaxf(m2, lrelu(as.z + ad.z)); m3 = fmaxf(m3, lrelu(as.w + ad.w));
    }
#pragma unroll
    for (int off = 1; off < 64; off <<= 1) {
        m0 = fmaxf(m0, __shfl_xor(m0, off)); m1 = fmaxf(m1, __shfl_xor(m1, off));
        m2 = fmaxf(m2, __shfl_xor(m2, off)); m3 = fmaxf(m3, __shfl_xor(m3, off));
    }

    // ---- phase 2: per-head sum of exp ----
    float s0 = 0.f, s1 = 0.f, s2 = 0.f, s3 = 0.f;
    if (has) {
        s0 = __expf(c0 - m0); s1 = __expf(c1 - m1);
        s2 = __expf(c2 - m2); s3 = __expf(c3 - m3);
    }
    for (int e = beg + lane + 64; e < end; e += 64) {
        int s = csr[e];
        float4 as = *(const float4*)(asrc + (size_t)s * 4);
        s0 += __expf(lrelu(as.x + ad.x) - m0); s1 += __expf(lrelu(as.y + ad.y) - m1);
        s2 += __expf(lrelu(as.z + ad.z) - m2); s3 += __expf(lrelu(as.w + ad.w) - m3);
    }
#pragma unroll
    for (int off = 1; off < 64; off <<= 1) {
        s0 += __shfl_xor(s0, off); s1 += __shfl_xor(s1, off);
        s2 += __shfl_xor(s2, off); s3 += __shfl_xor(s3, off);
    }
    float r0 = 1.f / (s0 + 1e-16f), r1 = 1.f / (s1 + 1e-16f);
    float r2 = 1.f / (s2 + 1e-16f), r3 = 1.f / (s3 + 1e-16f);

    // ---- phase 3: aggregate h[src]*alpha; lane owns features [4*lane,4*lane+4) ----
    float4 acc = make_float4(0.f, 0.f, 0.f, 0.f);
    for (int e = beg; e < end; ++e) {
        int s = csr[e];  // wave-uniform
        float4 as = *(const float4*)(asrc + (size_t)s * 4);
        float a0 = __expf(lrelu(as.x + ad.x) - m0) * r0;
        float a1 = __expf(lrelu(as.y + ad.y) - m1) * r1;
        float a2 = __expf(lrelu(as.z + ad.z) - m2) * r2;
        float a3 = __expf(lrelu(as.w + ad.w) - m3) * r3;
        float a = (lane < 16) ? a0 : (lane < 32) ? a1 : (lane < 48) ? a2 : a3;
        float4 hv = *(const float4*)(h + (size_t)s * 256 + lane * 4);
        acc.x = fmaf(hv.x, a, acc.x);
        acc.y = fmaf(hv.y, a, acc.y);
        acc.z = fmaf(hv.z, a, acc.z);
        acc.w = fmaf(hv.w, a, acc.w);
    }

    // ---- epilogue: BN + ReLU (+ log_softmax if FINAL) ----
    float4 sc = ((const float4*)scale)[lane];
    float4 sh = ((const float4*)shift)[lane];
    float t0 = fmaxf(fmaf(acc.x, sc.x, sh.x), 0.f);
    float t1 = fmaxf(fmaf(acc.y, sc.y, sh.y), 0.f);
    float t2 = fmaxf(fmaf(acc.z, sc.z, sh.z), 0.f);
    float t3 = fmaxf(fmaf(acc.w, sc.w, sh.w), 0.f);
    if (FINAL) {
        float m = fmaxf(fmaxf(t0, t1), fmaxf(t2, t3));
#pragma unroll
        for (int off = 1; off < 64; off <<= 1) m = fmaxf(m, __shfl_xor(m, off));
        float es = __expf(t0 - m) + __expf(t1 - m) + __expf(t2 - m) + __expf(t3 - m);
#pragma unroll
        for (int off = 1; off < 64; off <<= 1) es += __shfl_xor(es, off);
        float lse = m + logf(es);
        t0 -= lse; t1 -= lse; t2 -= lse; t3 -= lse;
    }
    *(float4*)(outp + (size_t)node * 256 + lane * 4) = make_float4(t0, t1, t2, t3);
}

extern "C" void kernel_launch(void* const* d_in, const int* in_sizes, int n_in,
                              void* d_out, int out_size, void* d_ws, size_t ws_size,
                              hipStream_t stream) {
    (void)in_sizes; (void)n_in; (void)out_size; (void)ws_size;
    const float* x   = (const float*)d_in[0];
    const int*   ei  = (const int*)d_in[1];
    const float* W1  = (const float*)d_in[2];
    const float* as1 = (const float*)d_in[3];
    const float* ad1 = (const float*)d_in[4];
    const float* b1  = (const float*)d_in[5];
    const float* g1  = (const float*)d_in[6];
    const float* be1 = (const float*)d_in[7];
    const float* m1  = (const float*)d_in[8];
    const float* v1  = (const float*)d_in[9];
    const float* W2  = (const float*)d_in[10];
    const float* as2 = (const float*)d_in[11];
    const float* ad2 = (const float*)d_in[12];
    const float* b2  = (const float*)d_in[13];
    const float* g2  = (const float*)d_in[14];
    const float* be2 = (const float*)d_in[15];
    const float* m2  = (const float*)d_in[16];
    const float* v2  = (const float*)d_in[17];

    float* out = (float*)d_out;
    // ws layout (floats): h[N*256] | asrc[N*4] | adst[N*4] | sc1,sh1,sc2,sh2[256 ea]
    // then (ints): deg/cursor[N] | offs[N+1] | csr_src[ET]
    float* h    = (float*)d_ws;
    float* asrc = h + (size_t)N_NODES * FDIM;
    float* adst = asrc + (size_t)N_NODES * 4;
    float* sc1  = adst + (size_t)N_NODES * 4;
    float* sh1  = sc1 + 256;
    float* sc2  = sh1 + 256;
    float* sh2  = sc2 + 256;
    int* deg    = (int*)(sh2 + 256);   // reused as cursor after scan
    int* offs   = deg + N_NODES;
    int* csr    = offs + N_NODES + 1;

    prep_bn_kernel<<<1, 256, 0, stream>>>(b1, g1, be1, m1, v1, b2, g2, be2, m2, v2,
                                          sc1, sh1, sc2, sh2);

    // ---- CSR build (once per call; reused by both layers) ----
    const int eb = (ET_EDGES + 255) / 256;
    hipMemsetAsync(deg, 0, N_NODES * sizeof(int), stream);
    deg_kernel<<<eb, 256, 0, stream>>>(ei, deg);
    scan_kernel<<<1, 1024, 0, stream>>>(deg, offs);
    hipMemsetAsync(deg, 0, N_NODES * sizeof(int), stream);  // now the scatter cursor
    scatter_kernel<<<eb, 256, 0, stream>>>(ei, offs, deg, csr);

    dim3 ggrid((N_NODES + 63) / 64, 4);
    const int nb = (N_NODES + 3) / 4;

    // ---- layer 1 ----
    gemm_kernel<128><<<ggrid, 256, 0, stream>>>(x, W1, h, N_NODES);
    adot_kernel<<<nb, 256, 0, stream>>>(h, as1, ad1, asrc, adst, N_NODES);
    gat_gather_kernel<false><<<nb, 256, 0, stream>>>(offs, csr, asrc, adst, h, sc1, sh1, out);

    // ---- layer 2 ----
    gemm_kernel<256><<<ggrid, 256, 0, stream>>>(out, W2, h, N_NODES);
    adot_kernel<<<nb, 256, 0, stream>>>(h, as2, ad2, asrc, adst, N_NODES);
    gat_gather_kernel<true><<<nb, 256, 0, stream>>>(offs, csr, asrc, adst, h, sc2, sh2, out);
}

// Round 3
// 458.463 us; speedup vs baseline: 14.4148x; 1.7758x over previous
//
#include <hip/hip_runtime.h>
#include <hip/hip_bf16.h>
#include <cstdint>

#define N_NODES 50000
#define N_EDGES 800000
#define ET_EDGES (N_EDGES + N_NODES)   // with self-loops
#define FDIM 256
#define BN_EPS 1e-5f

typedef short bf16x8 __attribute__((ext_vector_type(8)));   // 8 bf16 = 4 VGPRs
typedef float f32x4 __attribute__((ext_vector_type(4)));

__device__ __forceinline__ float lrelu(float x) { return x >= 0.f ? x : 0.2f * x; }
__device__ __forceinline__ float b2f(unsigned short u) {
    return __uint_as_float(((unsigned int)u) << 16);
}
__device__ __forceinline__ unsigned short f2b(float f) {   // RNE
    unsigned int u = __float_as_uint(f);
    u += 0x7fffu + ((u >> 16) & 1u);
    return (unsigned short)(u >> 16);
}

// ---------------- BN param prep ----------------
__global__ void prep_bn_kernel(const float* __restrict__ b1, const float* __restrict__ g1,
                               const float* __restrict__ be1, const float* __restrict__ m1,
                               const float* __restrict__ v1,
                               const float* __restrict__ b2, const float* __restrict__ g2,
                               const float* __restrict__ be2, const float* __restrict__ m2,
                               const float* __restrict__ v2,
                               float* sc1, float* sh1, float* sc2, float* sh2) {
    int f = threadIdx.x;
    float s1 = rsqrtf(v1[f] + BN_EPS) * g1[f];
    sc1[f] = s1;
    sh1[f] = (b1[f] - m1[f]) * s1 + be1[f];
    float s2 = rsqrtf(v2[f] + BN_EPS) * g2[f];
    sc2[f] = s2;
    sh2[f] = (b2[f] - m2[f]) * s2 + be2[f];
}

// ---------------- fp32 -> bf16 convert (x) ----------------
__global__ __launch_bounds__(256) void convx_kernel(const float* __restrict__ in,
                                                    unsigned short* __restrict__ out, int n4) {
    int i = blockIdx.x * 256 + threadIdx.x;
    if (i >= n4) return;
    float4 v = ((const float4*)in)[i];
    ushort4 o;
    o.x = f2b(v.x); o.y = f2b(v.y); o.z = f2b(v.z); o.w = f2b(v.w);
    ((ushort4*)out)[i] = o;
}

// ---------------- W [K x 256] -> W^T bf16 [256 x K] ----------------
__global__ __launch_bounds__(256) void wt_kernel(const float* __restrict__ W,
                                                 unsigned short* __restrict__ WT, int K) {
    int t = blockIdx.x * 256 + threadIdx.x;   // t over 256*K
    if (t >= 256 * K) return;
    int n = t / K, k = t - n * K;
    WT[t] = f2b(W[(size_t)k * 256 + n]);
}

// ---------------- CSR build ----------------
__global__ __launch_bounds__(256) void deg_kernel(const int* __restrict__ ei,
                                                  int* __restrict__ deg) {
    int e = blockIdx.x * 256 + threadIdx.x;
    if (e >= ET_EDGES) return;
    int d = (e < N_EDGES) ? ei[N_EDGES + e] : (e - N_EDGES);
    atomicAdd(&deg[d], 1);
}

__global__ __launch_bounds__(1024) void scan_kernel(const int* __restrict__ deg,
                                                    int* __restrict__ offs) {
    __shared__ int sums[1024];
    const int t = threadIdx.x;
    constexpr int CH = (N_NODES + 1023) / 1024;
    int local[CH];
    int base = t * CH;
    int s = 0;
#pragma unroll
    for (int i = 0; i < CH; ++i) {
        int idx = base + i;
        int v = (idx < N_NODES) ? deg[idx] : 0;
        local[i] = v;
        s += v;
    }
    sums[t] = s;
    __syncthreads();
    for (int off = 1; off < 1024; off <<= 1) {
        int y = (t >= off) ? sums[t - off] : 0;
        __syncthreads();
        sums[t] += y;
        __syncthreads();
    }
    int carry = sums[t] - s;
#pragma unroll
    for (int i = 0; i < CH; ++i) {
        int idx = base + i;
        if (idx < N_NODES) offs[idx] = carry;
        carry += local[i];
    }
    if (t == 0) offs[N_NODES] = ET_EDGES;
}

__global__ __launch_bounds__(256) void scatter_kernel(const int* __restrict__ ei,
                                                      const int* __restrict__ offs,
                                                      int* __restrict__ cursor,
                                                      int* __restrict__ csr) {
    int e = blockIdx.x * 256 + threadIdx.x;
    if (e >= ET_EDGES) return;
    int s, d;
    if (e < N_EDGES) { s = ei[e]; d = ei[N_EDGES + e]; }
    else             { s = d = e - N_EDGES; }
    int pos = offs[d] + atomicAdd(&cursor[d], 1);
    csr[pos] = s;
}

// ---------------- bf16 MFMA GEMM: H[M x 256] = A[M x K] @ W[K x 256], BT = W^T ----------------
// 128x128 tile, 4 waves, each wave 64x64 = 4x4 grid of 16x16x32 accums. BK=64.
template <int K>
__global__ __launch_bounds__(256) void gemm_bf16_kernel(const unsigned short* __restrict__ A,
                                                        const unsigned short* __restrict__ BT,
                                                        unsigned short* __restrict__ H, int M) {
    constexpr int BK = 64;
    __shared__ unsigned short As[128][BK + 8];   // row stride 72 (144B, 16B-aligned)
    __shared__ unsigned short Bs[128][BK + 8];
    const int tid = threadIdx.x;
    const int lane = tid & 63;
    const int w = tid >> 6;
    const int bm = blockIdx.x * 128;
    const int bn = blockIdx.y * 128;
    const int wr = (w >> 1) * 64;
    const int wc = (w & 1) * 64;

    f32x4 acc[4][4];
#pragma unroll
    for (int i = 0; i < 4; ++i)
#pragma unroll
        for (int j = 0; j < 4; ++j) acc[i][j] = (f32x4){0.f, 0.f, 0.f, 0.f};

    const int srow = tid >> 3;          // 0..31 per iter
    const int skc = (tid & 7) * 8;      // k offset

    for (int k0 = 0; k0 < K; k0 += BK) {
#pragma unroll
        for (int i = 0; i < 4; ++i) {
            int row = i * 32 + srow;
            int ar = bm + row; if (ar >= M) ar = M - 1;
            *(bf16x8*)&As[row][skc] = *(const bf16x8*)(A + (size_t)ar * K + k0 + skc);
            *(bf16x8*)&Bs[row][skc] = *(const bf16x8*)(BT + (size_t)(bn + row) * K + k0 + skc);
        }
        __syncthreads();
#pragma unroll
        for (int ks = 0; ks < BK; ks += 32) {
            int kk = ks + (lane >> 4) * 8;
            bf16x8 af[4], bf[4];
#pragma unroll
            for (int i = 0; i < 4; ++i) {
                af[i] = *(const bf16x8*)&As[wr + i * 16 + (lane & 15)][kk];
                bf[i] = *(const bf16x8*)&Bs[wc + i * 16 + (lane & 15)][kk];
            }
#pragma unroll
            for (int i = 0; i < 4; ++i)
#pragma unroll
                for (int j = 0; j < 4; ++j)
                    acc[i][j] = __builtin_amdgcn_mfma_f32_16x16x32_bf16(af[i], bf[j], acc[i][j], 0, 0, 0);
        }
        __syncthreads();
    }

    // C/D layout: col = lane&15, row = (lane>>4)*4 + reg
#pragma unroll
    for (int i = 0; i < 4; ++i) {
#pragma unroll
        for (int r = 0; r < 4; ++r) {
            int gr = bm + wr + i * 16 + (lane >> 4) * 4 + r;
            if (gr < M) {
#pragma unroll
                for (int j = 0; j < 4; ++j) {
                    int gc = bn + wc + j * 16 + (lane & 15);
                    H[(size_t)gr * 256 + gc] = f2b(acc[i][j][r]);
                }
            }
        }
    }
}

// ---------------- per-node attention dots from bf16 h ----------------
__global__ __launch_bounds__(256) void adot_kernel(const unsigned short* __restrict__ hb,
                                                   const float* __restrict__ a_src,
                                                   const float* __restrict__ a_dst,
                                                   float* __restrict__ asrc,
                                                   float* __restrict__ adst, int n) {
    int node = blockIdx.x * 4 + (threadIdx.x >> 6);
    if (node >= n) return;
    int lane = threadIdx.x & 63;
    ushort4 hv = *(const ushort4*)(hb + (size_t)node * 256 + lane * 4);
    float4 av = ((const float4*)a_src)[lane];
    float4 dv = ((const float4*)a_dst)[lane];
    float h0 = b2f(hv.x), h1 = b2f(hv.y), h2 = b2f(hv.z), h3 = b2f(hv.w);
    float ps = h0 * av.x + h1 * av.y + h2 * av.z + h3 * av.w;
    float pd = h0 * dv.x + h1 * dv.y + h2 * dv.z + h3 * dv.w;
#pragma unroll
    for (int off = 1; off < 16; off <<= 1) {
        ps += __shfl_xor(ps, off);
        pd += __shfl_xor(pd, off);
    }
    float s0 = __shfl(ps, 0), s1 = __shfl(ps, 16), s2 = __shfl(ps, 32), s3 = __shfl(ps, 48);
    float d0 = __shfl(pd, 0), d1 = __shfl(pd, 16), d2 = __shfl(pd, 32), d3 = __shfl(pd, 48);
    if (lane == 0) {
        *(float4*)(asrc + (size_t)node * 4) = make_float4(s0, s1, s2, s3);
        *(float4*)(adst + (size_t)node * 4) = make_float4(d0, d1, d2, d3);
    }
}

// ---------------- fused gather + softmax + aggregate + epilogue ----------------
// One wave per destination node; deg<=64 fast path caches alpha in LDS.
template <bool FINAL>
__global__ __launch_bounds__(256) void gat_gather_kernel(const int* __restrict__ offs,
                                                         const int* __restrict__ csr,
                                                         const float* __restrict__ asrc,
                                                         const float* __restrict__ adst,
                                                         const unsigned short* __restrict__ hb,
                                                         const float* __restrict__ scale,
                                                         const float* __restrict__ shift,
                                                         float* __restrict__ outf,
                                                         unsigned short* __restrict__ outb) {
    __shared__ int src_l[4][64];
    __shared__ float al[4][4][65];   // [wave][head][edge], padded to 65

    int wid = threadIdx.x >> 6;
    int node = blockIdx.x * 4 + wid;
    if (node >= N_NODES) return;
    int lane = threadIdx.x & 63;
    int beg = offs[node], end = offs[node + 1];
    int deg = end - beg;
    float4 ad = *(const float4*)(adst + (size_t)node * 4);
    int hsel = lane >> 4;

    float4 acc = make_float4(0.f, 0.f, 0.f, 0.f);

    if (deg <= 64) {
        // -------- fast path: lane <-> edge --------
        int s = 0;
        float c0 = -3.4e38f, c1 = -3.4e38f, c2 = -3.4e38f, c3 = -3.4e38f;
        if (lane < deg) {
            s = csr[beg + lane];
            float4 as = *(const float4*)(asrc + (size_t)s * 4);
            c0 = lrelu(as.x + ad.x); c1 = lrelu(as.y + ad.y);
            c2 = lrelu(as.z + ad.z); c3 = lrelu(as.w + ad.w);
        }
        float m0 = c0, m1 = c1, m2 = c2, m3 = c3;
#pragma unroll
        for (int off = 1; off < 64; off <<= 1) {
            m0 = fmaxf(m0, __shfl_xor(m0, off)); m1 = fmaxf(m1, __shfl_xor(m1, off));
            m2 = fmaxf(m2, __shfl_xor(m2, off)); m3 = fmaxf(m3, __shfl_xor(m3, off));
        }
        float e0 = 0.f, e1 = 0.f, e2 = 0.f, e3 = 0.f;
        if (lane < deg) {
            e0 = __expf(c0 - m0); e1 = __expf(c1 - m1);
            e2 = __expf(c2 - m2); e3 = __expf(c3 - m3);
        }
        float s0 = e0, s1 = e1, s2 = e2, s3 = e3;
#pragma unroll
        for (int off = 1; off < 64; off <<= 1) {
            s0 += __shfl_xor(s0, off); s1 += __shfl_xor(s1, off);
            s2 += __shfl_xor(s2, off); s3 += __shfl_xor(s3, off);
        }
        float r0 = 1.f / (s0 + 1e-16f), r1 = 1.f / (s1 + 1e-16f);
        float r2 = 1.f / (s2 + 1e-16f), r3 = 1.f / (s3 + 1e-16f);
        src_l[wid][lane] = s;
        al[wid][0][lane] = e0 * r0;
        al[wid][1][lane] = e1 * r1;
        al[wid][2][lane] = e2 * r2;
        al[wid][3][lane] = e3 * r3;
        __asm__ volatile("s_waitcnt lgkmcnt(0)" ::: "memory");  // wave-local LDS visibility

        int e = 0;
        for (; e + 1 < deg; e += 2) {
            int sa = src_l[wid][e], sb = src_l[wid][e + 1];
            float aa = al[wid][hsel][e], ab = al[wid][hsel][e + 1];
            ushort4 ha = *(const ushort4*)(hb + (size_t)sa * 256 + lane * 4);
            ushort4 hbv = *(const ushort4*)(hb + (size_t)sb * 256 + lane * 4);
            acc.x = fmaf(b2f(ha.x), aa, acc.x); acc.y = fmaf(b2f(ha.y), aa, acc.y);
            acc.z = fmaf(b2f(ha.z), aa, acc.z); acc.w = fmaf(b2f(ha.w), aa, acc.w);
            acc.x = fmaf(b2f(hbv.x), ab, acc.x); acc.y = fmaf(b2f(hbv.y), ab, acc.y);
            acc.z = fmaf(b2f(hbv.z), ab, acc.z); acc.w = fmaf(b2f(hbv.w), ab, acc.w);
        }
        if (e < deg) {
            int sa = src_l[wid][e];
            float aa = al[wid][hsel][e];
            ushort4 ha = *(const ushort4*)(hb + (size_t)sa * 256 + lane * 4);
            acc.x = fmaf(b2f(ha.x), aa, acc.x); acc.y = fmaf(b2f(ha.y), aa, acc.y);
            acc.z = fmaf(b2f(ha.z), aa, acc.z); acc.w = fmaf(b2f(ha.w), aa, acc.w);
        }
    } else {
        // -------- slow path (deg > 64): recompute per edge --------
        float m0 = -3.4e38f, m1 = -3.4e38f, m2 = -3.4e38f, m3 = -3.4e38f;
        for (int e = beg + lane; e < end; e += 64) {
            int s = csr[e];
            float4 as = *(const float4*)(asrc + (size_t)s * 4);
            m0 = fmaxf(m0, lrelu(as.x + ad.x)); m1 = fmaxf(m1, lrelu(as.y + ad.y));
            m2 = fmaxf(m2, lrelu(as.z + ad.z)); m3 = fmaxf(m3, lrelu(as.w + ad.w));
        }
#pragma unroll
        for (int off = 1; off < 64; off <<= 1) {
            m0 = fmaxf(m0, __shfl_xor(m0, off)); m1 = fmaxf(m1, __shfl_xor(m1, off));
            m2 = fmaxf(m2, __shfl_xor(m2, off)); m3 = fmaxf(m3, __shfl_xor(m3, off));
        }
        float s0 = 0.f, s1 = 0.f, s2 = 0.f, s3 = 0.f;
        for (int e = beg + lane; e < end; e += 64) {
            int s = csr[e];
            float4 as = *(const float4*)(asrc + (size_t)s * 4);
            s0 += __expf(lrelu(as.x + ad.x) - m0); s1 += __expf(lrelu(as.y + ad.y) - m1);
            s2 += __expf(lrelu(as.z + ad.z) - m2); s3 += __expf(lrelu(as.w + ad.w) - m3);
        }
#pragma unroll
        for (int off = 1; off < 64; off <<= 1) {
            s0 += __shfl_xor(s0, off); s1 += __shfl_xor(s1, off);
            s2 += __shfl_xor(s2, off); s3 += __shfl_xor(s3, off);
        }
        float r0 = 1.f / (s0 + 1e-16f), r1 = 1.f / (s1 + 1e-16f);
        float r2 = 1.f / (s2 + 1e-16f), r3 = 1.f / (s3 + 1e-16f);
        float mh = (hsel == 0) ? m0 : (hsel == 1) ? m1 : (hsel == 2) ? m2 : m3;
        float rh = (hsel == 0) ? r0 : (hsel == 1) ? r1 : (hsel == 2) ? r2 : r3;
        for (int e = beg; e < end; ++e) {
            int s = csr[e];
            float4 as = *(const float4*)(asrc + (size_t)s * 4);
            float sc4 = (hsel == 0) ? (as.x + ad.x) : (hsel == 1) ? (as.y + ad.y)
                       : (hsel == 2) ? (as.z + ad.z) : (as.w + ad.w);
            float a = __expf(lrelu(sc4) - mh) * rh;
            ushort4 hv = *(const ushort4*)(hb + (size_t)s * 256 + lane * 4);
            acc.x = fmaf(b2f(hv.x), a, acc.x); acc.y = fmaf(b2f(hv.y), a, acc.y);
            acc.z = fmaf(b2f(hv.z), a, acc.z); acc.w = fmaf(b2f(hv.w), a, acc.w);
        }
    }

    // ---- epilogue: BN + ReLU (+ log_softmax) ----
    float4 sc = ((const float4*)scale)[lane];
    float4 sh = ((const float4*)shift)[lane];
    float t0 = fmaxf(fmaf(acc.x, sc.x, sh.x), 0.f);
    float t1 = fmaxf(fmaf(acc.y, sc.y, sh.y), 0.f);
    float t2 = fmaxf(fmaf(acc.z, sc.z, sh.z), 0.f);
    float t3 = fmaxf(fmaf(acc.w, sc.w, sh.w), 0.f);
    if (FINAL) {
        float m = fmaxf(fmaxf(t0, t1), fmaxf(t2, t3));
#pragma unroll
        for (int off = 1; off < 64; off <<= 1) m = fmaxf(m, __shfl_xor(m, off));
        float es = __expf(t0 - m) + __expf(t1 - m) + __expf(t2 - m) + __expf(t3 - m);
#pragma unroll
        for (int off = 1; off < 64; off <<= 1) es += __shfl_xor(es, off);
        float lse = m + logf(es);
        *(float4*)(outf + (size_t)node * 256 + lane * 4) =
            make_float4(t0 - lse, t1 - lse, t2 - lse, t3 - lse);
    } else {
        ushort4 o;
        o.x = f2b(t0); o.y = f2b(t1); o.z = f2b(t2); o.w = f2b(t3);
        *(ushort4*)(outb + (size_t)node * 256 + lane * 4) = o;
    }
}

extern "C" void kernel_launch(void* const* d_in, const int* in_sizes, int n_in,
                              void* d_out, int out_size, void* d_ws, size_t ws_size,
                              hipStream_t stream) {
    (void)in_sizes; (void)n_in; (void)out_size; (void)ws_size;
    const float* x   = (const float*)d_in[0];
    const int*   ei  = (const int*)d_in[1];
    const float* W1  = (const float*)d_in[2];
    const float* as1 = (const float*)d_in[3];
    const float* ad1 = (const float*)d_in[4];
    const float* b1  = (const float*)d_in[5];
    const float* g1  = (const float*)d_in[6];
    const float* be1 = (const float*)d_in[7];
    const float* m1  = (const float*)d_in[8];
    const float* v1  = (const float*)d_in[9];
    const float* W2  = (const float*)d_in[10];
    const float* as2 = (const float*)d_in[11];
    const float* ad2 = (const float*)d_in[12];
    const float* b2  = (const float*)d_in[13];
    const float* g2  = (const float*)d_in[14];
    const float* be2 = (const float*)d_in[15];
    const float* m2  = (const float*)d_in[16];
    const float* v2  = (const float*)d_in[17];

    float* out = (float*)d_out;
    unsigned short* actb = (unsigned short*)d_out;  // layer-1 bf16 acts live in d_out until gemm2

    // ws layout (16B-aligned chunks): hb | xb | asrc | adst | sc/sh x4 | W1T | W2T | ints
    char* base = (char*)d_ws;
    unsigned short* hb  = (unsigned short*)base;                       base += (size_t)N_NODES * 256 * 2;
    unsigned short* xb  = (unsigned short*)base;                       base += (size_t)N_NODES * 128 * 2;
    float* asrc = (float*)base;                                        base += (size_t)N_NODES * 4 * 4;
    float* adst = (float*)base;                                        base += (size_t)N_NODES * 4 * 4;
    float* sc1 = (float*)base;                                         base += 1024;
    float* sh1 = (float*)base;                                         base += 1024;
    float* sc2 = (float*)base;                                         base += 1024;
    float* sh2 = (float*)base;                                         base += 1024;
    unsigned short* W1T = (unsigned short*)base;                       base += 256 * 128 * 2;
    unsigned short* W2T = (unsigned short*)base;                       base += 256 * 256 * 2;
    int* deg  = (int*)base;                                            base += N_NODES * 4;
    int* offs = (int*)base;                                            base += (N_NODES + 1) * 4;
    int* csr  = (int*)base;

    prep_bn_kernel<<<1, 256, 0, stream>>>(b1, g1, be1, m1, v1, b2, g2, be2, m2, v2,
                                          sc1, sh1, sc2, sh2);
    convx_kernel<<<(N_NODES * 128 / 4 + 255) / 256, 256, 0, stream>>>(x, xb, N_NODES * 128 / 4);
    wt_kernel<<<(256 * 128 + 255) / 256, 256, 0, stream>>>(W1, W1T, 128);
    wt_kernel<<<(256 * 256 + 255) / 256, 256, 0, stream>>>(W2, W2T, 256);

    // CSR build
    const int eb = (ET_EDGES + 255) / 256;
    hipMemsetAsync(deg, 0, N_NODES * sizeof(int), stream);
    deg_kernel<<<eb, 256, 0, stream>>>(ei, deg);
    scan_kernel<<<1, 1024, 0, stream>>>(deg, offs);
    hipMemsetAsync(deg, 0, N_NODES * sizeof(int), stream);
    scatter_kernel<<<eb, 256, 0, stream>>>(ei, offs, deg, csr);

    dim3 ggrid((N_NODES + 127) / 128, 2);
    const int nb = (N_NODES + 3) / 4;

    // ---- layer 1 ----
    gemm_bf16_kernel<128><<<ggrid, 256, 0, stream>>>(xb, W1T, hb, N_NODES);
    adot_kernel<<<nb, 256, 0, stream>>>(hb, as1, ad1, asrc, adst, N_NODES);
    gat_gather_kernel<false><<<nb, 256, 0, stream>>>(offs, csr, asrc, adst, hb, sc1, sh1,
                                                     nullptr, actb);

    // ---- layer 2 ----
    gemm_bf16_kernel<256><<<ggrid, 256, 0, stream>>>(actb, W2T, hb, N_NODES);
    adot_kernel<<<nb, 256, 0, stream>>>(hb, as2, ad2, asrc, adst, N_NODES);
    gat_gather_kernel<true><<<nb, 256, 0, stream>>>(offs, csr, asrc, adst, hb, sc2, sh2,
                                                    out, nullptr);
}